// Round 5
// baseline (218.388 us; speedup 1.0000x reference)
//
#include <hip/hip_runtime.h>
#include <math.h>

// Problem constants: N=20000, E=320000, IN=128, H*HID=128,
// layer2: 128 -> 4, final linear heads->1, output = mean over nodes.
// Scores bounded (0.05-scale weights) -> softmax without max-subtraction.
// Layer-1 GEMMs on bf16 MFMA. K/V packed as u32 (K hi, V lo); Q/S likewise
// packed as u32 (Q hi, S lo) -- output is a mean over 20000 nodes so bf16
// rounding contracts ~sqrt(N) (measured 3e-5 with KV alone).
// Layer-2 QKVS projection (128->16) fused into the l1 aggregation epilogue.
// R2 lesson (measured): cooperative grid.sync costs ~50us/sync on MI355X
// (csr_coop = 238us @ 0.25% VALUBusy) -- NEVER use grid-wide sync here.
// R3: fixed-capacity bucket CSR (cap=64 slots/node); degree atomic's return
// value IS the scatter slot (deg ~ Poisson(16), P(>64) ~ 2e-18).
// R4 lesson (measured, absmax fail 3.4e-4): __shfl inside a loop whose trip
// count differs between wave halves reads INACTIVE source lanes ->
// ds_bpermute returns 0. ALL __shfl must run under uniform exec: uniform
// 8-slot main steps + fully-unrolled masked tail (clamped slot index).
// R7 lesson: never co-locate latency-bound scatter blocks with MFMA blocks
// in one grid (4% VALU / 2% MFMA, 2.5x slower than separate dispatches).
static constexpr float EPS_PYG = 1e-16f;
static constexpr float INV_SQRT32 = 0.17677669529663687f; // 1/sqrt(32)
static constexpr int CAP = 64;            // bucket capacity per node
static constexpr int CAP_SH = 6;          // log2(CAP)

typedef short bf16x8 __attribute__((ext_vector_type(8)));
typedef float f32x4 __attribute__((ext_vector_type(4)));

__device__ inline unsigned short f2bf(float f) {   // RNE f32 -> bf16
    union { float f; unsigned u; } x; x.f = f;
    unsigned r = x.u + 0x7FFFu + ((x.u >> 16) & 1u);
    return (unsigned short)(r >> 16);
}
__device__ inline float bf_hi(unsigned u) {        // high 16 bits as bf16
    union { unsigned u; float f; } x; x.u = u & 0xFFFF0000u; return x.f;
}
__device__ inline float bf_lo(unsigned u) {        // low 16 bits as bf16
    union { unsigned u; float f; } x; x.u = u << 16; return x.f;
}

// -------- fused: degree atomic + direct bucket scatter + W1 transpose + out init
__global__ __launch_bounds__(256) void build_csr_kernel(
    const int* __restrict__ src, const int* __restrict__ dst,
    int* __restrict__ deg, int* __restrict__ csr_src,
    int E, int nblk_deg,
    const float* __restrict__ Wq, const float* __restrict__ Wk,
    const float* __restrict__ Wv, const float* __restrict__ Wsk,
    unsigned short* __restrict__ Wbt,
    float* __restrict__ out, const float* __restrict__ bl)
{
    const int b = blockIdx.x;
    const int t = threadIdx.x;
    if (b < nblk_deg) {
        int e = b * 256 + t;
        if (e < E) {
            int d = dst[e];
            int s = atomicAdd(&deg[d], 1);
            if (s < CAP) csr_src[(d << CAP_SH) + s] = src[e];
        }
    } else if (b < nblk_deg + 4) {
        int m = b - nblk_deg;
        const float* W = (m == 0) ? Wq : (m == 1) ? Wk : (m == 2) ? Wv : Wsk;
        for (int i = t; i < 16384; i += 256) {
            int k = i >> 7, nn = i & 127;
            Wbt[(m << 14) + nn * 128 + k] = f2bf(W[i]);
        }
    } else {
        if (t == 0) out[0] = bl[0];
    }
}

// ------------------------------------------------- Layer-1 QKVS GEMM (MFMA)
// grid=(ceil(n/64)): one block per 64-row tile. A-fragments (f32->bf16
// inline) are loaded ONCE into registers; an unrolled mode loop computes
// {Q,S} then {K,V} reusing them (X read once, not twice).
// Fragment layouts (m89/m91/m118-verified):
//   A: lane holds A[m=lane&15][k=kc+quad*8+j]; B: B[k=kc+quad*8+j][n=lane&15]
//   D: col=lane&15, row=quad*4+reg
__global__ __launch_bounds__(256) void gemm1_mfma(
    const float* __restrict__ X, const unsigned short* __restrict__ Wbt,
    const float* __restrict__ bq, const float* __restrict__ bk,
    const float* __restrict__ bv, const float* __restrict__ bsk,
    unsigned int* __restrict__ QS, unsigned int* __restrict__ KV, int n)
{
    const int tid  = threadIdx.x;
    const int wave = tid >> 6;
    const int lane = tid & 63;
    const int m    = lane & 15;
    const int quad = lane >> 4;
    const int r0   = blockIdx.x * 64 + wave * 16;

    int arow = r0 + m;
    if (arow >= n) arow = n - 1;              // safe clamp; stores are masked

    const float4* xr = (const float4*)(X + (size_t)arow * 128);

    // load + convert the four A-fragments once (16 VGPRs)
    bf16x8 afr[4];
#pragma unroll
    for (int kc4 = 0; kc4 < 4; ++kc4) {
        float4 f0 = xr[kc4 * 8 + quad * 2];
        float4 f1 = xr[kc4 * 8 + quad * 2 + 1];
        bf16x8 a;
        a[0] = (short)f2bf(f0.x); a[1] = (short)f2bf(f0.y);
        a[2] = (short)f2bf(f0.z); a[3] = (short)f2bf(f0.w);
        a[4] = (short)f2bf(f1.x); a[5] = (short)f2bf(f1.y);
        a[6] = (short)f2bf(f1.z); a[7] = (short)f2bf(f1.w);
        afr[kc4] = a;
    }

#pragma unroll
    for (int mode = 0; mode < 2; ++mode) {
        const unsigned short* WA = Wbt + (size_t)(mode ? 1 : 0) * 16384; // Q or K
        const unsigned short* WB = Wbt + (size_t)(mode ? 2 : 3) * 16384; // V or S
        const float* biasA = mode ? bk : bq;
        const float* biasB = mode ? bv : bsk;
        unsigned int* Out = mode ? KV : QS;

        f32x4 accA[8] = {};
        f32x4 accB[8] = {};
#pragma unroll
        for (int kc4 = 0; kc4 < 4; ++kc4) {
            const int koff = kc4 * 32 + quad * 8;
#pragma unroll
            for (int ct = 0; ct < 8; ++ct) {
                bf16x8 ba = *(const bf16x8*)(WA + (ct * 16 + m) * 128 + koff);
                accA[ct] = __builtin_amdgcn_mfma_f32_16x16x32_bf16(afr[kc4], ba, accA[ct], 0, 0, 0);
                bf16x8 bb = *(const bf16x8*)(WB + (ct * 16 + m) * 128 + koff);
                accB[ct] = __builtin_amdgcn_mfma_f32_16x16x32_bf16(afr[kc4], bb, accB[ct], 0, 0, 0);
            }
        }
#pragma unroll
        for (int ct = 0; ct < 8; ++ct) {
            const int col = ct * 16 + m;
            const float bA = biasA[col], bB = biasB[col];
#pragma unroll
            for (int r = 0; r < 4; ++r) {
                const int row = r0 + quad * 4 + r;
                if (row < n) {
                    unsigned ha = f2bf(accA[ct][r] + bA);
                    unsigned lb = f2bf(accB[ct][r] + bB);
                    Out[(size_t)row * 128 + col] = (ha << 16) | lb;
                }
            }
        }
    }
}

// ------- Layer-1 per-node softmax + aggregate + fused layer-2 projection
// ONE FULL WAVE (64 lanes) per node: two 32-lane halves split the edge list
// (stride-2 interleave), each lane covers 4 channels (cbase mapping), dot
// reduced with 3 width-8 shuffles; halves merged with one __shfl_xor(..,32).
// Bucket preloaded with ONE coalesced 256B load (lane lf owns slot lf);
// gather indices distributed via __shfl. ALL __shfl run under uniform exec:
// main loop steps 8 slots with uniform condition (p_base+8 <= cnt); tail is
// a fully-unrolled 4-iteration masked loop (slot clamped to cnt-1, e zeroed
// when invalid), guarded by uniform (p_base < cnt).
// Epilogue: fused layer-2 projection through W2{q,k,v,s} (128->16) in-wave.
__global__ __launch_bounds__(256) void l1_agg_kernel(
    const unsigned int* __restrict__ QS, const unsigned int* __restrict__ KV,
    const int* __restrict__ deg, const int* __restrict__ csr_src,
    const float* __restrict__ W2q, const float* __restrict__ W2k,
    const float* __restrict__ W2v, const float* __restrict__ W2s,
    const float* __restrict__ b2q, const float* __restrict__ b2k,
    const float* __restrict__ b2v, const float* __restrict__ b2s,
    float4* __restrict__ Q2, float4* __restrict__ KV2, float4* __restrict__ S2,
    int n)
{
    const int t = threadIdx.x;
    const int node = blockIdx.x * 4 + (t >> 6);
    if (node >= n) return;
    const int l    = t & 31;          // channel lane within half
    const int half = (t >> 5) & 1;    // which 32-lane half of the wave
    const int lf   = t & 63;          // lane within wave
    const int cbase = ((l >> 3) << 5) + ((l & 7) << 2);   // head*32 + sub*4

    const int beg = node << CAP_SH;
    int cnt = deg[node]; if (cnt > CAP) cnt = CAP;

    // preload the whole bucket: lane lf owns slot lf (garbage past cnt unused)
    const int eall = csr_src[beg + lf];

    const uint4 qs = *(const uint4*)(QS + (size_t)node * 128 + cbase);
    const float4 q = make_float4(bf_hi(qs.x), bf_hi(qs.y), bf_hi(qs.z), bf_hi(qs.w));

    float lsum = 0.f, a0 = 0.f, a1 = 0.f, a2 = 0.f, a3 = 0.f;
    int p_base = 0;
    for (; p_base + 8 <= cnt; p_base += 8) {   // uniform: all 8 slots valid
        const int p = p_base + half;
        int s0 = __shfl(eall, p, 64);
        int s1 = __shfl(eall, p + 2, 64);
        int s2 = __shfl(eall, p + 4, 64);
        int s3 = __shfl(eall, p + 6, 64);
        uint4 u0 = *(const uint4*)(KV + (size_t)s0 * 128 + cbase);
        uint4 u1 = *(const uint4*)(KV + (size_t)s1 * 128 + cbase);
        uint4 u2 = *(const uint4*)(KV + (size_t)s2 * 128 + cbase);
        uint4 u3 = *(const uint4*)(KV + (size_t)s3 * 128 + cbase);
        float p0 = q.x * bf_hi(u0.x) + q.y * bf_hi(u0.y)
                 + q.z * bf_hi(u0.z) + q.w * bf_hi(u0.w);
        float p1 = q.x * bf_hi(u1.x) + q.y * bf_hi(u1.y)
                 + q.z * bf_hi(u1.z) + q.w * bf_hi(u1.w);
        float p2 = q.x * bf_hi(u2.x) + q.y * bf_hi(u2.y)
                 + q.z * bf_hi(u2.z) + q.w * bf_hi(u2.w);
        float p3 = q.x * bf_hi(u3.x) + q.y * bf_hi(u3.y)
                 + q.z * bf_hi(u3.z) + q.w * bf_hi(u3.w);
        p0 += __shfl_xor(p0, 4, 8);  p1 += __shfl_xor(p1, 4, 8);
        p2 += __shfl_xor(p2, 4, 8);  p3 += __shfl_xor(p3, 4, 8);
        p0 += __shfl_xor(p0, 2, 8);  p1 += __shfl_xor(p1, 2, 8);
        p2 += __shfl_xor(p2, 2, 8);  p3 += __shfl_xor(p3, 2, 8);
        p0 += __shfl_xor(p0, 1, 8);  p1 += __shfl_xor(p1, 1, 8);
        p2 += __shfl_xor(p2, 1, 8);  p3 += __shfl_xor(p3, 1, 8);
        float e0 = __expf(p0 * INV_SQRT32);
        float e1 = __expf(p1 * INV_SQRT32);
        float e2 = __expf(p2 * INV_SQRT32);
        float e3 = __expf(p3 * INV_SQRT32);
        lsum += (e0 + e1) + (e2 + e3);
        a0 += e0 * bf_lo(u0.x) + e1 * bf_lo(u1.x)
            + e2 * bf_lo(u2.x) + e3 * bf_lo(u3.x);
        a1 += e0 * bf_lo(u0.y) + e1 * bf_lo(u1.y)
            + e2 * bf_lo(u2.y) + e3 * bf_lo(u3.y);
        a2 += e0 * bf_lo(u0.z) + e1 * bf_lo(u1.z)
            + e2 * bf_lo(u2.z) + e3 * bf_lo(u3.z);
        a3 += e0 * bf_lo(u0.w) + e1 * bf_lo(u1.w)
            + e2 * bf_lo(u2.w) + e3 * bf_lo(u3.w);
    }
    if (p_base < cnt) {               // uniform guard; <=7 slots remain
        const int pclamp = cnt - 1;   // cnt >= 1 here
#pragma unroll
        for (int j = 0; j < 4; ++j) { // uniform trip count, all lanes active
            int p = p_base + half + 2 * j;
            const bool valid = p < cnt;
            int ps = valid ? p : pclamp;          // clamped: always a written slot
            int s0 = __shfl(eall, ps, 64);        // full-wave exec -> safe
            uint4 u0 = *(const uint4*)(KV + (size_t)s0 * 128 + cbase);
            float p0 = q.x * bf_hi(u0.x) + q.y * bf_hi(u0.y)
                     + q.z * bf_hi(u0.z) + q.w * bf_hi(u0.w);
            p0 += __shfl_xor(p0, 4, 8);
            p0 += __shfl_xor(p0, 2, 8);
            p0 += __shfl_xor(p0, 1, 8);
            float e0 = valid ? __expf(p0 * INV_SQRT32) : 0.f;
            lsum += e0;
            a0 += e0 * bf_lo(u0.x);
            a1 += e0 * bf_lo(u0.y);
            a2 += e0 * bf_lo(u0.z);
            a3 += e0 * bf_lo(u0.w);
        }
    }
    // merge the two 32-lane halves (lanes l and l+32 hold same channels)
    lsum += __shfl_xor(lsum, 32, 64);
    a0   += __shfl_xor(a0,   32, 64);
    a1   += __shfl_xor(a1,   32, 64);
    a2   += __shfl_xor(a2,   32, 64);
    a3   += __shfl_xor(a3,   32, 64);

    // H1 channels for this lane (relu'd); skip values from packed QS lo bits
    const float inv = 1.0f / (lsum + EPS_PYG);
    const float h0 = fmaxf(a0 * inv + bf_lo(qs.x), 0.f);
    const float h1 = fmaxf(a1 * inv + bf_lo(qs.y), 0.f);
    const float h2 = fmaxf(a2 * inv + bf_lo(qs.z), 0.f);
    const float h3 = fmaxf(a3 * inv + bf_lo(qs.w), 0.f);

    // fused layer-2 projection: half 0 -> (Q2, K2), half 1 -> (V2, S2)
    const float* WA = half ? W2v : W2q;
    const float* WB = half ? W2s : W2k;
    float p0, p1, p2, p3, p4, p5, p6, p7;
    {
        float4 wa = *(const float4*)(WA + (size_t)(cbase + 0) * 4);
        float4 wb = *(const float4*)(WB + (size_t)(cbase + 0) * 4);
        p0 = h0 * wa.x; p1 = h0 * wa.y; p2 = h0 * wa.z; p3 = h0 * wa.w;
        p4 = h0 * wb.x; p5 = h0 * wb.y; p6 = h0 * wb.z; p7 = h0 * wb.w;
        wa = *(const float4*)(WA + (size_t)(cbase + 1) * 4);
        wb = *(const float4*)(WB + (size_t)(cbase + 1) * 4);
        p0 += h1 * wa.x; p1 += h1 * wa.y; p2 += h1 * wa.z; p3 += h1 * wa.w;
        p4 += h1 * wb.x; p5 += h1 * wb.y; p6 += h1 * wb.z; p7 += h1 * wb.w;
        wa = *(const float4*)(WA + (size_t)(cbase + 2) * 4);
        wb = *(const float4*)(WB + (size_t)(cbase + 2) * 4);
        p0 += h2 * wa.x; p1 += h2 * wa.y; p2 += h2 * wa.z; p3 += h2 * wa.w;
        p4 += h2 * wb.x; p5 += h2 * wb.y; p6 += h2 * wb.z; p7 += h2 * wb.w;
        wa = *(const float4*)(WA + (size_t)(cbase + 3) * 4);
        wb = *(const float4*)(WB + (size_t)(cbase + 3) * 4);
        p0 += h3 * wa.x; p1 += h3 * wa.y; p2 += h3 * wa.z; p3 += h3 * wa.w;
        p4 += h3 * wb.x; p5 += h3 * wb.y; p6 += h3 * wb.z; p7 += h3 * wb.w;
    }
#pragma unroll
    for (int mk = 16; mk >= 1; mk >>= 1) {
        p0 += __shfl_xor(p0, mk, 32); p1 += __shfl_xor(p1, mk, 32);
        p2 += __shfl_xor(p2, mk, 32); p3 += __shfl_xor(p3, mk, 32);
        p4 += __shfl_xor(p4, mk, 32); p5 += __shfl_xor(p5, mk, 32);
        p6 += __shfl_xor(p6, mk, 32); p7 += __shfl_xor(p7, mk, 32);
    }
    if (lf == 0) {                    // half 0 writer: Q2 + K half of KV2
        const float4 ba = *(const float4*)b2q;
        const float4 bb = *(const float4*)b2k;
        Q2[node] = make_float4(p0 + ba.x, p1 + ba.y, p2 + ba.z, p3 + ba.w);
        KV2[(size_t)node * 2 + 0] =
            make_float4(p4 + bb.x, p5 + bb.y, p6 + bb.z, p7 + bb.w);
    } else if (lf == 32) {            // half 1 writer: V half of KV2 + S2
        const float4 ba = *(const float4*)b2v;
        const float4 bb = *(const float4*)b2s;
        KV2[(size_t)node * 2 + 1] =
            make_float4(p0 + ba.x, p1 + ba.y, p2 + ba.z, p3 + ba.w);
        S2[node] = make_float4(p4 + bb.x, p5 + bb.y, p6 + bb.z, p7 + bb.w);
    }
}

// --------------------- Layer-2 softmax/aggregate + final linear + mean
// 16-lane group per node; lane-owned edge stripes + width-16 butterfly.
__global__ __launch_bounds__(256) void l2_agg_kernel(
    const float4* __restrict__ Q2, const float4* __restrict__ KV2,
    const float4* __restrict__ S2,
    const int* __restrict__ deg, const int* __restrict__ csr_src,
    const float* __restrict__ Wl, float* __restrict__ out, int n, float invn)
{
    const int t  = threadIdx.x;
    const int g  = t >> 4;
    const int gl = t & 15;
    const int nd = blockIdx.x * 16 + g;
    float y = 0.f;
    if (nd < n) {
        const int beg = nd << CAP_SH;
        int cnt = deg[nd]; if (cnt > CAP) cnt = CAP;
        const int end = beg + cnt;
        float4 q = Q2[nd];
        float l0 = 0.f, l1 = 0.f, l2 = 0.f, l3 = 0.f;
        float a0 = 0.f, a1 = 0.f, a2 = 0.f, a3 = 0.f;
        for (int pos = beg + gl; pos < end; pos += 16) {
            int src = csr_src[pos];
            float4 k = KV2[(size_t)src * 2 + 0];
            float4 v = KV2[(size_t)src * 2 + 1];
            float e0 = __expf(q.x * k.x);
            float e1 = __expf(q.y * k.y);
            float e2 = __expf(q.z * k.z);
            float e3 = __expf(q.w * k.w);
            l0 += e0; a0 += e0 * v.x;
            l1 += e1; a1 += e1 * v.y;
            l2 += e2; a2 += e2 * v.z;
            l3 += e3; a3 += e3 * v.w;
        }
#pragma unroll
        for (int mk = 8; mk >= 1; mk >>= 1) {
            l0 += __shfl_xor(l0, mk, 16); l1 += __shfl_xor(l1, mk, 16);
            l2 += __shfl_xor(l2, mk, 16); l3 += __shfl_xor(l3, mk, 16);
            a0 += __shfl_xor(a0, mk, 16); a1 += __shfl_xor(a1, mk, 16);
            a2 += __shfl_xor(a2, mk, 16); a3 += __shfl_xor(a3, mk, 16);
        }
        if (gl == 0) {
            float4 sk = S2[nd];
            float h0 = a0 / (l0 + EPS_PYG) + sk.x;
            float h1 = a1 / (l1 + EPS_PYG) + sk.y;
            float h2 = a2 / (l2 + EPS_PYG) + sk.z;
            float h3 = a3 / (l3 + EPS_PYG) + sk.w;
            y = (h0 * Wl[0] + h1 * Wl[1] + h2 * Wl[2] + h3 * Wl[3]) * invn;
        }
    }
    __shared__ float red[256];
    red[t] = y;
    __syncthreads();
    for (int off = 128; off > 0; off >>= 1) {
        if (t < (unsigned)off) red[t] += red[t + off];
        __syncthreads();
    }
    if (t == 0) atomicAdd(out, red[0]);
}

// ---------------------------------------------------------------- launcher
extern "C" void kernel_launch(void* const* d_in, const int* in_sizes, int n_in,
                              void* d_out, int out_size, void* d_ws, size_t ws_size,
                              hipStream_t stream) {
    const float* x        = (const float*)d_in[0];
    const int*   edge_src = (const int*)d_in[1];
    const int*   edge_dst = (const int*)d_in[2];
    const float* W1q = (const float*)d_in[3];  const float* b1q = (const float*)d_in[4];
    const float* W1k = (const float*)d_in[5];  const float* b1k = (const float*)d_in[6];
    const float* W1v = (const float*)d_in[7];  const float* b1v = (const float*)d_in[8];
    const float* W1s = (const float*)d_in[9];  const float* b1s = (const float*)d_in[10];
    const float* W2q = (const float*)d_in[11]; const float* b2q = (const float*)d_in[12];
    const float* W2k = (const float*)d_in[13]; const float* b2k = (const float*)d_in[14];
    const float* W2v = (const float*)d_in[15]; const float* b2v = (const float*)d_in[16];
    const float* W2s = (const float*)d_in[17]; const float* b2s = (const float*)d_in[18];
    const float* Wl  = (const float*)d_in[19]; const float* bl  = (const float*)d_in[20];

    const int N = in_sizes[0] / 128;
    const int E = in_sizes[1];
    float* out = (float*)d_out;

    // ---- workspace layout (16B-aligned sections) ----
    float* ws  = (float*)d_ws;
    size_t off = 0;
    unsigned int* QS  = (unsigned int*)(ws + off); off += (size_t)N * 128; // packed bf16 (Q hi, S lo)
    unsigned int* KV  = (unsigned int*)(ws + off); off += (size_t)N * 128; // packed bf16 (K hi, V lo)
    float*        q2  = ws + off; off += (size_t)N * 4;
    float*        kv2 = ws + off; off += (size_t)N * 8;   // [node]{k4,v4} interleaved
    float*        s2  = ws + off; off += (size_t)N * 4;
    unsigned short* Wbt = (unsigned short*)(ws + off); off += 4 * 16384 / 2;  // 4 mats bf16
    int* deg     = (int*)(ws + off);            // N
    int* csr_src = deg + N;                     // N * CAP bucket rows

    const int nblk_e = (E + 255) / 256;     // 1250
    const int nblk_g = (N + 63) / 64;       // 313

    // 1) zero degree counters (80 KB)
    hipMemsetAsync(deg, 0, (size_t)N * sizeof(int), stream);
    // 2) fused degree+scatter (bucket CSR)  ||  W1 transpose  ||  out init
    build_csr_kernel<<<nblk_e + 5, 256, 0, stream>>>(
        edge_src, edge_dst, deg, csr_src, E, nblk_e,
        W1q, W1k, W1v, W1s, Wbt, out, bl);
    // 3) layer-1 QKVS MFMA GEMM (A loaded once, in-register mode loop)
    gemm1_mfma<<<nblk_g, 256, 0, stream>>>(x, Wbt, b1q, b1k, b1v, b1s,
                                           QS, KV, N);
    // 4) layer-1 softmax + aggregate + ReLU + fused layer-2 QKVS projection
    l1_agg_kernel<<<(N + 3) / 4, 256, 0, stream>>>(
        QS, KV, deg, csr_src, W2q, W2k, W2v, W2s, b2q, b2k, b2v, b2s,
        (float4*)q2, (float4*)kv2, (float4*)s2, N);
    // 5) layer-2 softmax/aggregate + final linear + mean
    l2_agg_kernel<<<(N + 15) / 16, 256, 0, stream>>>((const float4*)q2,
                                                     (const float4*)kv2,
                                                     (const float4*)s2,
                                                     deg, csr_src, Wl, out, N,
                                                     1.0f / (float)N);
}

// Round 6
// 208.727 us; speedup vs baseline: 1.0463x; 1.0463x over previous
//
#include <hip/hip_runtime.h>
#include <math.h>

// Problem constants: N=20000, E=320000, IN=128, H*HID=128,
// layer2: 128 -> 4, final linear heads->1, output = mean over nodes.
// Scores bounded (0.05-scale weights) -> softmax without max-subtraction.
// Layer-1 GEMMs on bf16 MFMA. K/V packed as u32 (K hi, V lo); Q/S likewise
// packed as u32 (Q hi, S lo) -- output is a mean over 20000 nodes so bf16
// rounding contracts ~sqrt(N) (measured 3e-5 with KV alone).
// Layer-2 QKVS projection (128->16) fused into the l1 aggregation epilogue.
// R2 lesson (measured): cooperative grid.sync costs ~50us/sync on MI355X
// (csr_coop = 238us @ 0.25% VALUBusy) -- NEVER use grid-wide sync here.
// R3: fixed-capacity bucket CSR (cap=64 slots/node); degree atomic's return
// value IS the scatter slot (deg ~ Poisson(16), P(>64) ~ 2e-18).
// R4 lesson (measured, absmax fail 3.4e-4): __shfl inside a loop whose trip
// count differs between wave halves reads INACTIVE source lanes ->
// ds_bpermute returns 0. ALL __shfl must run under uniform exec.
// R5 lesson (measured): gemm1 with 1252 waves = 1.2 waves/SIMD ran at 2%
// MfmaUtil, 44us -- occupancy-starved latency bound. Wave count >> per-wave
// arithmetic reuse for these tiny GEMMs. build_csr at 1 edge/thread = 45us,
// 0.2% VALU -- single load->atomic->store chain per thread has no MLP.
// R7 lesson: never co-locate latency-bound scatter blocks with MFMA blocks
// in one grid (4% VALU / 2% MFMA, 2.5x slower than separate dispatches).
static constexpr float EPS_PYG = 1e-16f;
static constexpr float INV_SQRT32 = 0.17677669529663687f; // 1/sqrt(32)
static constexpr int CAP = 64;            // bucket capacity per node
static constexpr int CAP_SH = 6;          // log2(CAP)

typedef short bf16x8 __attribute__((ext_vector_type(8)));
typedef float f32x4 __attribute__((ext_vector_type(4)));

__device__ inline unsigned short f2bf(float f) {   // RNE f32 -> bf16
    union { float f; unsigned u; } x; x.f = f;
    unsigned r = x.u + 0x7FFFu + ((x.u >> 16) & 1u);
    return (unsigned short)(r >> 16);
}
__device__ inline float bf_hi(unsigned u) {        // high 16 bits as bf16
    union { unsigned u; float f; } x; x.u = u & 0xFFFF0000u; return x.f;
}
__device__ inline float bf_lo(unsigned u) {        // low 16 bits as bf16
    union { unsigned u; float f; } x; x.u = u << 16; return x.f;
}

// -------- fused: degree atomic + direct bucket scatter + W1 transpose + out init
// R5: 4 edges per thread (1024 per block) -- hoisted loads, 4 independent
// atomics in flight, then 4 stores: 4x MLP on the atomic-return chain.
__global__ __launch_bounds__(256) void build_csr_kernel(
    const int* __restrict__ src, const int* __restrict__ dst,
    int* __restrict__ deg, int* __restrict__ csr_src,
    int E, int nblk_deg,
    const float* __restrict__ Wq, const float* __restrict__ Wk,
    const float* __restrict__ Wv, const float* __restrict__ Wsk,
    unsigned short* __restrict__ Wbt,
    float* __restrict__ out, const float* __restrict__ bl)
{
    const int b = blockIdx.x;
    const int t = threadIdx.x;
    if (b < nblk_deg) {
        const int e0 = b * 1024 + t;
        const int e1 = e0 + 256, e2 = e0 + 512, e3 = e0 + 768;
        const bool v0 = e0 < E, v1 = e1 < E, v2 = e2 < E, v3 = e3 < E;
        int d0 = 0, d1 = 0, d2 = 0, d3 = 0;
        int s0 = 0, s1 = 0, s2 = 0, s3 = 0;
        if (v0) { d0 = dst[e0]; s0 = src[e0]; }
        if (v1) { d1 = dst[e1]; s1 = src[e1]; }
        if (v2) { d2 = dst[e2]; s2 = src[e2]; }
        if (v3) { d3 = dst[e3]; s3 = src[e3]; }
        int sl0 = 0, sl1 = 0, sl2 = 0, sl3 = 0;
        if (v0) sl0 = atomicAdd(&deg[d0], 1);
        if (v1) sl1 = atomicAdd(&deg[d1], 1);
        if (v2) sl2 = atomicAdd(&deg[d2], 1);
        if (v3) sl3 = atomicAdd(&deg[d3], 1);
        if (v0 && sl0 < CAP) csr_src[(d0 << CAP_SH) + sl0] = s0;
        if (v1 && sl1 < CAP) csr_src[(d1 << CAP_SH) + sl1] = s1;
        if (v2 && sl2 < CAP) csr_src[(d2 << CAP_SH) + sl2] = s2;
        if (v3 && sl3 < CAP) csr_src[(d3 << CAP_SH) + sl3] = s3;
    } else if (b < nblk_deg + 4) {
        int m = b - nblk_deg;
        const float* W = (m == 0) ? Wq : (m == 1) ? Wk : (m == 2) ? Wv : Wsk;
        for (int i = t; i < 16384; i += 256) {
            int k = i >> 7, nn = i & 127;
            Wbt[(m << 14) + nn * 128 + k] = f2bf(W[i]);
        }
    } else {
        if (t == 0) out[0] = bl[0];
    }
}

// ------------------------------------------------- Layer-1 QKVS GEMM (MFMA)
// grid=(ceil(n/64), 4): y = mode*2 + cthalf. Each wave: 16 rows x 4 ct x
// 2 mats = 32 MFMA -> 5008 waves (4.9/SIMD) for latency hiding (R5 lesson).
// A-fragments (f32->bf16 inline) loaded once per wave; X re-read 4x across
// y-blocks is L3-resident.
// Fragment layouts (m89/m91/m118-verified):
//   A: lane holds A[m=lane&15][k=kc+quad*8+j]; B: B[k=kc+quad*8+j][n=lane&15]
//   D: col=lane&15, row=quad*4+reg
__global__ __launch_bounds__(256) void gemm1_mfma(
    const float* __restrict__ X, const unsigned short* __restrict__ Wbt,
    const float* __restrict__ bq, const float* __restrict__ bk,
    const float* __restrict__ bv, const float* __restrict__ bsk,
    unsigned int* __restrict__ QS, unsigned int* __restrict__ KV, int n)
{
    const int mode  = blockIdx.y >> 1;    // 0 = Q+S, 1 = K+V
    const int chalf = blockIdx.y & 1;     // output-column half (ct 0-3 / 4-7)

    const int tid  = threadIdx.x;
    const int wave = tid >> 6;
    const int lane = tid & 63;
    const int m    = lane & 15;
    const int quad = lane >> 4;
    const int r0   = blockIdx.x * 64 + wave * 16;

    int arow = r0 + m;
    if (arow >= n) arow = n - 1;              // safe clamp; stores are masked

    const float4* xr = (const float4*)(X + (size_t)arow * 128);

    // load + convert the four A-fragments once (16 VGPRs)
    bf16x8 afr[4];
#pragma unroll
    for (int kc4 = 0; kc4 < 4; ++kc4) {
        float4 f0 = xr[kc4 * 8 + quad * 2];
        float4 f1 = xr[kc4 * 8 + quad * 2 + 1];
        bf16x8 a;
        a[0] = (short)f2bf(f0.x); a[1] = (short)f2bf(f0.y);
        a[2] = (short)f2bf(f0.z); a[3] = (short)f2bf(f0.w);
        a[4] = (short)f2bf(f1.x); a[5] = (short)f2bf(f1.y);
        a[6] = (short)f2bf(f1.z); a[7] = (short)f2bf(f1.w);
        afr[kc4] = a;
    }

    const unsigned short* WA = Wbt + (size_t)(mode ? 1 : 0) * 16384; // Q or K
    const unsigned short* WB = Wbt + (size_t)(mode ? 2 : 3) * 16384; // V or S
    const float* biasA = mode ? bk : bq;
    const float* biasB = mode ? bv : bsk;
    unsigned int* Out = mode ? KV : QS;

    f32x4 accA[4] = {};
    f32x4 accB[4] = {};
#pragma unroll
    for (int kc4 = 0; kc4 < 4; ++kc4) {
        const int koff = kc4 * 32 + quad * 8;
#pragma unroll
        for (int c = 0; c < 4; ++c) {
            const int ct = chalf * 4 + c;
            bf16x8 ba = *(const bf16x8*)(WA + (ct * 16 + m) * 128 + koff);
            accA[c] = __builtin_amdgcn_mfma_f32_16x16x32_bf16(afr[kc4], ba, accA[c], 0, 0, 0);
            bf16x8 bb = *(const bf16x8*)(WB + (ct * 16 + m) * 128 + koff);
            accB[c] = __builtin_amdgcn_mfma_f32_16x16x32_bf16(afr[kc4], bb, accB[c], 0, 0, 0);
        }
    }
#pragma unroll
    for (int c = 0; c < 4; ++c) {
        const int col = (chalf * 4 + c) * 16 + m;
        const float bA = biasA[col], bB = biasB[col];
#pragma unroll
        for (int r = 0; r < 4; ++r) {
            const int row = r0 + quad * 4 + r;
            if (row < n) {
                unsigned ha = f2bf(accA[c][r] + bA);
                unsigned lb = f2bf(accB[c][r] + bB);
                Out[(size_t)row * 128 + col] = (ha << 16) | lb;
            }
        }
    }
}

// ------- Layer-1 per-node softmax + aggregate + fused layer-2 projection
// ONE FULL WAVE (64 lanes) per node: two 32-lane halves split the edge list
// (stride-2 interleave), each lane covers 4 channels (cbase mapping), dot
// reduced with 3 width-8 shuffles; halves merged with one __shfl_xor(..,32).
// Bucket preloaded with ONE coalesced 256B load (lane lf owns slot lf);
// gather indices distributed via __shfl. ALL __shfl run under uniform exec:
// main loop steps 8 slots with uniform condition (p_base+8 <= cnt); tail is
// a fully-unrolled 4-iteration masked loop (slot clamped to cnt-1, e zeroed
// when invalid), guarded by uniform (p_base < cnt).
// Epilogue: fused layer-2 projection through W2{q,k,v,s} (128->16) in-wave.
__global__ __launch_bounds__(256) void l1_agg_kernel(
    const unsigned int* __restrict__ QS, const unsigned int* __restrict__ KV,
    const int* __restrict__ deg, const int* __restrict__ csr_src,
    const float* __restrict__ W2q, const float* __restrict__ W2k,
    const float* __restrict__ W2v, const float* __restrict__ W2s,
    const float* __restrict__ b2q, const float* __restrict__ b2k,
    const float* __restrict__ b2v, const float* __restrict__ b2s,
    float4* __restrict__ Q2, float4* __restrict__ KV2, float4* __restrict__ S2,
    int n)
{
    const int t = threadIdx.x;
    const int node = blockIdx.x * 4 + (t >> 6);
    if (node >= n) return;
    const int l    = t & 31;          // channel lane within half
    const int half = (t >> 5) & 1;    // which 32-lane half of the wave
    const int lf   = t & 63;          // lane within wave
    const int cbase = ((l >> 3) << 5) + ((l & 7) << 2);   // head*32 + sub*4

    const int beg = node << CAP_SH;
    int cnt = deg[node]; if (cnt > CAP) cnt = CAP;

    // preload the whole bucket: lane lf owns slot lf (garbage past cnt unused)
    const int eall = csr_src[beg + lf];

    const uint4 qs = *(const uint4*)(QS + (size_t)node * 128 + cbase);
    const float4 q = make_float4(bf_hi(qs.x), bf_hi(qs.y), bf_hi(qs.z), bf_hi(qs.w));

    float lsum = 0.f, a0 = 0.f, a1 = 0.f, a2 = 0.f, a3 = 0.f;
    int p_base = 0;
    for (; p_base + 8 <= cnt; p_base += 8) {   // uniform: all 8 slots valid
        const int p = p_base + half;
        int s0 = __shfl(eall, p, 64);
        int s1 = __shfl(eall, p + 2, 64);
        int s2 = __shfl(eall, p + 4, 64);
        int s3 = __shfl(eall, p + 6, 64);
        uint4 u0 = *(const uint4*)(KV + (size_t)s0 * 128 + cbase);
        uint4 u1 = *(const uint4*)(KV + (size_t)s1 * 128 + cbase);
        uint4 u2 = *(const uint4*)(KV + (size_t)s2 * 128 + cbase);
        uint4 u3 = *(const uint4*)(KV + (size_t)s3 * 128 + cbase);
        float p0 = q.x * bf_hi(u0.x) + q.y * bf_hi(u0.y)
                 + q.z * bf_hi(u0.z) + q.w * bf_hi(u0.w);
        float p1 = q.x * bf_hi(u1.x) + q.y * bf_hi(u1.y)
                 + q.z * bf_hi(u1.z) + q.w * bf_hi(u1.w);
        float p2 = q.x * bf_hi(u2.x) + q.y * bf_hi(u2.y)
                 + q.z * bf_hi(u2.z) + q.w * bf_hi(u2.w);
        float p3 = q.x * bf_hi(u3.x) + q.y * bf_hi(u3.y)
                 + q.z * bf_hi(u3.z) + q.w * bf_hi(u3.w);
        p0 += __shfl_xor(p0, 4, 8);  p1 += __shfl_xor(p1, 4, 8);
        p2 += __shfl_xor(p2, 4, 8);  p3 += __shfl_xor(p3, 4, 8);
        p0 += __shfl_xor(p0, 2, 8);  p1 += __shfl_xor(p1, 2, 8);
        p2 += __shfl_xor(p2, 2, 8);  p3 += __shfl_xor(p3, 2, 8);
        p0 += __shfl_xor(p0, 1, 8);  p1 += __shfl_xor(p1, 1, 8);
        p2 += __shfl_xor(p2, 1, 8);  p3 += __shfl_xor(p3, 1, 8);
        float e0 = __expf(p0 * INV_SQRT32);
        float e1 = __expf(p1 * INV_SQRT32);
        float e2 = __expf(p2 * INV_SQRT32);
        float e3 = __expf(p3 * INV_SQRT32);
        lsum += (e0 + e1) + (e2 + e3);
        a0 += e0 * bf_lo(u0.x) + e1 * bf_lo(u1.x)
            + e2 * bf_lo(u2.x) + e3 * bf_lo(u3.x);
        a1 += e0 * bf_lo(u0.y) + e1 * bf_lo(u1.y)
            + e2 * bf_lo(u2.y) + e3 * bf_lo(u3.y);
        a2 += e0 * bf_lo(u0.z) + e1 * bf_lo(u1.z)
            + e2 * bf_lo(u2.z) + e3 * bf_lo(u3.z);
        a3 += e0 * bf_lo(u0.w) + e1 * bf_lo(u1.w)
            + e2 * bf_lo(u2.w) + e3 * bf_lo(u3.w);
    }
    if (p_base < cnt) {               // uniform guard; <=7 slots remain
        const int pclamp = cnt - 1;   // cnt >= 1 here
#pragma unroll
        for (int j = 0; j < 4; ++j) { // uniform trip count, all lanes active
            int p = p_base + half + 2 * j;
            const bool valid = p < cnt;
            int ps = valid ? p : pclamp;          // clamped: always a written slot
            int s0 = __shfl(eall, ps, 64);        // full-wave exec -> safe
            uint4 u0 = *(const uint4*)(KV + (size_t)s0 * 128 + cbase);
            float p0 = q.x * bf_hi(u0.x) + q.y * bf_hi(u0.y)
                     + q.z * bf_hi(u0.z) + q.w * bf_hi(u0.w);
            p0 += __shfl_xor(p0, 4, 8);
            p0 += __shfl_xor(p0, 2, 8);
            p0 += __shfl_xor(p0, 1, 8);
            float e0 = valid ? __expf(p0 * INV_SQRT32) : 0.f;
            lsum += e0;
            a0 += e0 * bf_lo(u0.x);
            a1 += e0 * bf_lo(u0.y);
            a2 += e0 * bf_lo(u0.z);
            a3 += e0 * bf_lo(u0.w);
        }
    }
    // merge the two 32-lane halves (lanes l and l+32 hold same channels)
    lsum += __shfl_xor(lsum, 32, 64);
    a0   += __shfl_xor(a0,   32, 64);
    a1   += __shfl_xor(a1,   32, 64);
    a2   += __shfl_xor(a2,   32, 64);
    a3   += __shfl_xor(a3,   32, 64);

    // H1 channels for this lane (relu'd); skip values from packed QS lo bits
    const float inv = 1.0f / (lsum + EPS_PYG);
    const float h0 = fmaxf(a0 * inv + bf_lo(qs.x), 0.f);
    const float h1 = fmaxf(a1 * inv + bf_lo(qs.y), 0.f);
    const float h2 = fmaxf(a2 * inv + bf_lo(qs.z), 0.f);
    const float h3 = fmaxf(a3 * inv + bf_lo(qs.w), 0.f);

    // fused layer-2 projection: half 0 -> (Q2, K2), half 1 -> (V2, S2)
    const float* WA = half ? W2v : W2q;
    const float* WB = half ? W2s : W2k;
    float p0, p1, p2, p3, p4, p5, p6, p7;
    {
        float4 wa = *(const float4*)(WA + (size_t)(cbase + 0) * 4);
        float4 wb = *(const float4*)(WB + (size_t)(cbase + 0) * 4);
        p0 = h0 * wa.x; p1 = h0 * wa.y; p2 = h0 * wa.z; p3 = h0 * wa.w;
        p4 = h0 * wb.x; p5 = h0 * wb.y; p6 = h0 * wb.z; p7 = h0 * wb.w;
        wa = *(const float4*)(WA + (size_t)(cbase + 1) * 4);
        wb = *(const float4*)(WB + (size_t)(cbase + 1) * 4);
        p0 += h1 * wa.x; p1 += h1 * wa.y; p2 += h1 * wa.z; p3 += h1 * wa.w;
        p4 += h1 * wb.x; p5 += h1 * wb.y; p6 += h1 * wb.z; p7 += h1 * wb.w;
        wa = *(const float4*)(WA + (size_t)(cbase + 2) * 4);
        wb = *(const float4*)(WB + (size_t)(cbase + 2) * 4);
        p0 += h2 * wa.x; p1 += h2 * wa.y; p2 += h2 * wa.z; p3 += h2 * wa.w;
        p4 += h2 * wb.x; p5 += h2 * wb.y; p6 += h2 * wb.z; p7 += h2 * wb.w;
        wa = *(const float4*)(WA + (size_t)(cbase + 3) * 4);
        wb = *(const float4*)(WB + (size_t)(cbase + 3) * 4);
        p0 += h3 * wa.x; p1 += h3 * wa.y; p2 += h3 * wa.z; p3 += h3 * wa.w;
        p4 += h3 * wb.x; p5 += h3 * wb.y; p6 += h3 * wb.z; p7 += h3 * wb.w;
    }
#pragma unroll
    for (int mk = 16; mk >= 1; mk >>= 1) {
        p0 += __shfl_xor(p0, mk, 32); p1 += __shfl_xor(p1, mk, 32);
        p2 += __shfl_xor(p2, mk, 32); p3 += __shfl_xor(p3, mk, 32);
        p4 += __shfl_xor(p4, mk, 32); p5 += __shfl_xor(p5, mk, 32);
        p6 += __shfl_xor(p6, mk, 32); p7 += __shfl_xor(p7, mk, 32);
    }
    if (lf == 0) {                    // half 0 writer: Q2 + K half of KV2
        const float4 ba = *(const float4*)b2q;
        const float4 bb = *(const float4*)b2k;
        Q2[node] = make_float4(p0 + ba.x, p1 + ba.y, p2 + ba.z, p3 + ba.w);
        KV2[(size_t)node * 2 + 0] =
            make_float4(p4 + bb.x, p5 + bb.y, p6 + bb.z, p7 + bb.w);
    } else if (lf == 32) {            // half 1 writer: V half of KV2 + S2
        const float4 ba = *(const float4*)b2v;
        const float4 bb = *(const float4*)b2s;
        KV2[(size_t)node * 2 + 1] =
            make_float4(p0 + ba.x, p1 + ba.y, p2 + ba.z, p3 + ba.w);
        S2[node] = make_float4(p4 + bb.x, p5 + bb.y, p6 + bb.z, p7 + bb.w);
    }
}

// --------------------- Layer-2 softmax/aggregate + final linear + mean
// 16-lane group per node; lane-owned edge stripes + width-16 butterfly.
__global__ __launch_bounds__(256) void l2_agg_kernel(
    const float4* __restrict__ Q2, const float4* __restrict__ KV2,
    const float4* __restrict__ S2,
    const int* __restrict__ deg, const int* __restrict__ csr_src,
    const float* __restrict__ Wl, float* __restrict__ out, int n, float invn)
{
    const int t  = threadIdx.x;
    const int g  = t >> 4;
    const int gl = t & 15;
    const int nd = blockIdx.x * 16 + g;
    float y = 0.f;
    if (nd < n) {
        const int beg = nd << CAP_SH;
        int cnt = deg[nd]; if (cnt > CAP) cnt = CAP;
        const int end = beg + cnt;
        float4 q = Q2[nd];
        float l0 = 0.f, l1 = 0.f, l2 = 0.f, l3 = 0.f;
        float a0 = 0.f, a1 = 0.f, a2 = 0.f, a3 = 0.f;
        for (int pos = beg + gl; pos < end; pos += 16) {
            int src = csr_src[pos];
            float4 k = KV2[(size_t)src * 2 + 0];
            float4 v = KV2[(size_t)src * 2 + 1];
            float e0 = __expf(q.x * k.x);
            float e1 = __expf(q.y * k.y);
            float e2 = __expf(q.z * k.z);
            float e3 = __expf(q.w * k.w);
            l0 += e0; a0 += e0 * v.x;
            l1 += e1; a1 += e1 * v.y;
            l2 += e2; a2 += e2 * v.z;
            l3 += e3; a3 += e3 * v.w;
        }
#pragma unroll
        for (int mk = 8; mk >= 1; mk >>= 1) {
            l0 += __shfl_xor(l0, mk, 16); l1 += __shfl_xor(l1, mk, 16);
            l2 += __shfl_xor(l2, mk, 16); l3 += __shfl_xor(l3, mk, 16);
            a0 += __shfl_xor(a0, mk, 16); a1 += __shfl_xor(a1, mk, 16);
            a2 += __shfl_xor(a2, mk, 16); a3 += __shfl_xor(a3, mk, 16);
        }
        if (gl == 0) {
            float4 sk = S2[nd];
            float h0 = a0 / (l0 + EPS_PYG) + sk.x;
            float h1 = a1 / (l1 + EPS_PYG) + sk.y;
            float h2 = a2 / (l2 + EPS_PYG) + sk.z;
            float h3 = a3 / (l3 + EPS_PYG) + sk.w;
            y = (h0 * Wl[0] + h1 * Wl[1] + h2 * Wl[2] + h3 * Wl[3]) * invn;
        }
    }
    __shared__ float red[256];
    red[t] = y;
    __syncthreads();
    for (int off = 128; off > 0; off >>= 1) {
        if (t < (unsigned)off) red[t] += red[t + off];
        __syncthreads();
    }
    if (t == 0) atomicAdd(out, red[0]);
}

// ---------------------------------------------------------------- launcher
extern "C" void kernel_launch(void* const* d_in, const int* in_sizes, int n_in,
                              void* d_out, int out_size, void* d_ws, size_t ws_size,
                              hipStream_t stream) {
    const float* x        = (const float*)d_in[0];
    const int*   edge_src = (const int*)d_in[1];
    const int*   edge_dst = (const int*)d_in[2];
    const float* W1q = (const float*)d_in[3];  const float* b1q = (const float*)d_in[4];
    const float* W1k = (const float*)d_in[5];  const float* b1k = (const float*)d_in[6];
    const float* W1v = (const float*)d_in[7];  const float* b1v = (const float*)d_in[8];
    const float* W1s = (const float*)d_in[9];  const float* b1s = (const float*)d_in[10];
    const float* W2q = (const float*)d_in[11]; const float* b2q = (const float*)d_in[12];
    const float* W2k = (const float*)d_in[13]; const float* b2k = (const float*)d_in[14];
    const float* W2v = (const float*)d_in[15]; const float* b2v = (const float*)d_in[16];
    const float* W2s = (const float*)d_in[17]; const float* b2s = (const float*)d_in[18];
    const float* Wl  = (const float*)d_in[19]; const float* bl  = (const float*)d_in[20];

    const int N = in_sizes[0] / 128;
    const int E = in_sizes[1];
    float* out = (float*)d_out;

    // ---- workspace layout (16B-aligned sections) ----
    float* ws  = (float*)d_ws;
    size_t off = 0;
    unsigned int* QS  = (unsigned int*)(ws + off); off += (size_t)N * 128; // packed bf16 (Q hi, S lo)
    unsigned int* KV  = (unsigned int*)(ws + off); off += (size_t)N * 128; // packed bf16 (K hi, V lo)
    float*        q2  = ws + off; off += (size_t)N * 4;
    float*        kv2 = ws + off; off += (size_t)N * 8;   // [node]{k4,v4} interleaved
    float*        s2  = ws + off; off += (size_t)N * 4;
    unsigned short* Wbt = (unsigned short*)(ws + off); off += 4 * 16384 / 2;  // 4 mats bf16
    int* deg     = (int*)(ws + off);            // N
    int* csr_src = deg + N;                     // N * CAP bucket rows

    const int nblk_e4 = (E + 1023) / 1024;  // 313 (4 edges/thread)
    const int nblk_g  = (N + 63) / 64;      // 313

    // 1) zero degree counters (80 KB)
    hipMemsetAsync(deg, 0, (size_t)N * sizeof(int), stream);
    // 2) fused degree+scatter (bucket CSR, 4-edge MLP)  ||  W1 transpose  ||  out init
    build_csr_kernel<<<nblk_e4 + 5, 256, 0, stream>>>(
        edge_src, edge_dst, deg, csr_src, E, nblk_e4,
        W1q, W1k, W1v, W1s, Wbt, out, bl);
    // 3) layer-1 QKVS MFMA GEMM (y = mode*2 + cthalf; 5008 waves)
    {
        dim3 grid(nblk_g, 4);
        gemm1_mfma<<<grid, 256, 0, stream>>>(x, Wbt, b1q, b1k, b1v, b1s,
                                             QS, KV, N);
    }
    // 4) layer-1 softmax + aggregate + ReLU + fused layer-2 QKVS projection
    l1_agg_kernel<<<(N + 3) / 4, 256, 0, stream>>>(
        QS, KV, deg, csr_src, W2q, W2k, W2v, W2s, b2q, b2k, b2v, b2s,
        (float4*)q2, (float4*)kv2, (float4*)s2, N);
    // 5) layer-2 softmax/aggregate + final linear + mean
    l2_agg_kernel<<<(N + 15) / 16, 256, 0, stream>>>((const float4*)q2,
                                                     (const float4*)kv2,
                                                     (const float4*)s2,
                                                     deg, csr_src, Wl, out, N,
                                                     1.0f / (float)N);
}